// Round 7
// baseline (387.362 us; speedup 1.0000x reference)
//
#include <hip/hip_runtime.h>

// B=2,H=16,S=2048,D=128 (f32 I/O; internal bf16 MFMA)
//   qk = x1·x2^T*scale + mask;  P = softmax_k(qk);  out = x3 @ P
// ws (58.7 MB): x1s=bf16(x1*scale), x2b=bf16(x2), x3s=bf16(x3*rl), mbf=bf16(mask)
// R7 lever: BOTH kernels were grid-limited to 2 blocks/CU (512 blocks/256 CU,
// Occupancy ~20%, MfmaUtil ~25 + VALUBusy ~33 = 58% busy, 42% stall).
// Split tiles to 1024 blocks each:
//   k_qk : q-stripe 64, LDS = sK 32KB -> 4 blocks/CU (16 waves).
//          Q-frags direct global->reg (16 VGPR, loaded once). Masks inline.
//   k_out: k-block 64; LDS 48KB via sE ALIASED into sQ (sE written only after
//          a barrier when QK's sQ reads are done; 4 barriers/iter) -> 3
//          blocks/CU (12 waves). bk register cache REVERTED (R6: conflicts
//          -35% but time +4us — conflicts weren't on the critical path).
//   exp via __expf; bf16 pack via pack2bf (v_perm round-half-up).
// LDS swizzle: 16B chunk c of row r stored at (c ^ (r&7)) -> bank-uniform for
// both row-staging writes and column-pattern fragment reads.

typedef __attribute__((ext_vector_type(8))) short short8;
typedef __attribute__((ext_vector_type(4))) float f32x4;

#define S_LEN 2048
#define D_LEN 128
#define BH_N 32
#define SCALE_QK 0.08838834764831845f

__device__ __forceinline__ unsigned short f2bf(float f) {
    union { float f; unsigned int i; } v; v.f = f;
    unsigned int r = v.i + 0x7FFFu + ((v.i >> 16) & 1u);  // RNE
    return (unsigned short)(r >> 16);
}
__device__ __forceinline__ float bf2f(unsigned short u) {
    union { unsigned int i; float f; } v; v.i = ((unsigned int)u) << 16; return v.f;
}
// pack two f32 -> two bf16 (round-half-up): 2 adds + 1 v_perm
__device__ __forceinline__ unsigned pack2bf(float a, float b) {
    unsigned ua = __float_as_uint(a) + 0x8000u;
    unsigned ub = __float_as_uint(b) + 0x8000u;
    return __builtin_amdgcn_perm(ub, ua, 0x07060302);  // [ua.b2,ua.b3,ub.b2,ub.b3]
}
__device__ __forceinline__ uint2 pack4bf(float4 v) {
    uint2 p;
    p.x = pack2bf(v.x, v.y);
    p.y = pack2bf(v.z, v.w);
    return p;
}

// ---------- Kernel 0: one-time f32 -> bf16 conversions ----------
__global__ void k_cvt(const float* __restrict__ x1,
                      const float* __restrict__ x2,
                      const float* __restrict__ mask,
                      unsigned short* __restrict__ x1s,
                      unsigned short* __restrict__ x2b,
                      unsigned short* __restrict__ mbf) {
    const size_t N1 = (size_t)BH_N * S_LEN * D_LEN;
    const size_t NM = (size_t)S_LEN * S_LEN;
    size_t i = ((size_t)blockIdx.x * 256 + threadIdx.x) * 4;
    if (i < N1) {
        float4 v = *(const float4*)&x1[i];
        v.x *= SCALE_QK; v.y *= SCALE_QK; v.z *= SCALE_QK; v.w *= SCALE_QK;
        *(uint2*)&x1s[i] = pack4bf(v);
    } else if (i < 2 * N1) {
        size_t j = i - N1;
        float4 v = *(const float4*)&x2[j];
        *(uint2*)&x2b[j] = pack4bf(v);
    } else if (i < 2 * N1 + NM) {
        size_t j = i - 2 * N1;
        float4 v = *(const float4*)&mask[j];
        *(uint2*)&mbf[j] = pack4bf(v);
    }
}

// ---------- Kernel 1: rowsums (C[q][k], A=x1 in regs) + x3s stripe ----------
// grid(32, 32): x = 64-row q stripe, y = bh. 4 waves, 4 blocks/CU.
// Wave w owns q rows [16w, 16w+16): acc[kb], kb in {0..7}.
__global__ __launch_bounds__(256, 4) void k_qk(
    const unsigned short* __restrict__ x1s,
    const unsigned short* __restrict__ x2b,
    const unsigned short* __restrict__ mbf,
    const float* __restrict__ x3,
    unsigned short* __restrict__ x3s)
{
    __shared__ unsigned short sK[128 * 128];  // k x d bf16 (per-iter, swizzled)
    __shared__ float sRL[64];
    const int q0 = blockIdx.x * 64;
    const int bh = blockIdx.y;
    const unsigned short* x1p = x1s + (size_t)bh * S_LEN * D_LEN;
    const unsigned short* x2p = x2b + (size_t)bh * S_LEN * D_LEN;
    const int t = threadIdx.x;
    const int w = t >> 6, lane = t & 63, quad = lane >> 4, l16 = lane & 15;

    // Q fragments in registers: wave-private, iteration-invariant. 16 VGPRs.
    short8 aq[4];
#pragma unroll
    for (int kk = 0; kk < 4; ++kk)
        aq[kk] = *(const short8*)&x1p[(size_t)(q0 + 16 * w + l16) * D_LEN
                                       + (kk * 4 + quad) * 8];

    float rs[4] = {0.f, 0.f, 0.f, 0.f};

    for (int k0 = 0; k0 < S_LEN; k0 += 128) {
        __syncthreads();
#pragma unroll
        for (int i = 0; i < 8; ++i) {  // stage sK (128x128), swizzled
            int idx = i * 256 + t;
            int r = idx >> 4, c = idx & 15;
            *(uint4*)&sK[r * 128 + ((c ^ (r & 7)) * 8)] =
                *(const uint4*)&x2p[(size_t)(k0 + r) * D_LEN + c * 8];
        }
        __syncthreads();

        f32x4 acc[8];
#pragma unroll
        for (int kb = 0; kb < 8; ++kb) acc[kb] = (f32x4){0.f, 0.f, 0.f, 0.f};

#pragma unroll
        for (int kk = 0; kk < 4; ++kk) {
            const int sc = ((kk * 4 + quad) ^ (l16 & 7)) * 8;
            short8 b[8];
#pragma unroll
            for (int kb = 0; kb < 8; ++kb)
                b[kb] = *(const short8*)&sK[(kb * 16 + l16) * 128 + sc];
#pragma unroll
            for (int kb = 0; kb < 8; ++kb)
                acc[kb] = __builtin_amdgcn_mfma_f32_16x16x32_bf16(aq[kk], b[kb], acc[kb], 0, 0, 0);
        }

        // exp + rowsum, masks inline; C row = q = 16w+4quad+rr, col = kb*16+l16
#pragma unroll
        for (int kb = 0; kb < 8; ++kb) {
            const size_t mrow = (size_t)(q0 + 16 * w + 4 * quad) * S_LEN
                                + k0 + kb * 16 + l16;
#pragma unroll
            for (int rr = 0; rr < 4; ++rr)
                rs[rr] += __expf(acc[kb][rr] + bf2f(mbf[mrow + (size_t)rr * S_LEN]));
        }
    }

    // each wave owns its 16 q rows: reduce over l16 (cols), write 1/sum
#pragma unroll
    for (int i = 0; i < 4; ++i) {
        float v = rs[i];
        v += __shfl_xor(v, 1); v += __shfl_xor(v, 2);
        v += __shfl_xor(v, 4); v += __shfl_xor(v, 8);
        if (l16 == 0) sRL[16 * w + 4 * quad + i] = 1.0f / v;
    }
    __syncthreads();

    // x3s[:, q0:q0+64] = bf16(x3 * rl)
    const float* x3b = x3 + (size_t)bh * (size_t)D_LEN * S_LEN;
    unsigned short* x3sp = x3s + (size_t)bh * (size_t)D_LEN * S_LEN;
#pragma unroll
    for (int i = 0; i < 8; ++i) {
        int e = (i * 256 + t) * 4;
        int r = e >> 6, c = e & 63;
        float4 v = *(const float4*)&x3b[(size_t)r * S_LEN + q0 + c];
        v.x *= sRL[c]; v.y *= sRL[c + 1]; v.z *= sRL[c + 2]; v.w *= sRL[c + 3];
        *(uint2*)&x3sp[(size_t)r * S_LEN + q0 + c] = pack4bf(v);
    }
}

// ---------- Kernel 2: out = x3s @ exp(QK + mask), 64-k blocks ----------
// grid(32, 32): x = 64-col k block, y = bh. 4 waves, 3 blocks/CU.
// QK: wave w owns q rows [16w,16w+16) x 64k. PV: wave w owns d [32w,32w+32).
// sE (64k x 64q, 8KB) ALIASES sQ — separated by barriers (4/iter).
__global__ __launch_bounds__(256, 3) void k_out(
    const unsigned short* __restrict__ x1s,
    const unsigned short* __restrict__ x2b,
    const unsigned short* __restrict__ x3s,
    const unsigned short* __restrict__ mbf,
    float* __restrict__ out)
{
    __shared__ unsigned short sK[64 * 128];   // x2 k-block (resident, swizzled) 16KB
    __shared__ unsigned short sQ[64 * 128];   // x1 q-tile (swizzled) 16KB
    __shared__ unsigned short sX[128 * 64];   // x3s tile d x q (swizzled) 16KB
    unsigned short* sE = sQ;                  // E^T k x q (64x64, 8KB) — alias
    const int kb0 = blockIdx.x * 64;
    const int bh = blockIdx.y;
    const unsigned short* x1p = x1s + (size_t)bh * S_LEN * D_LEN;
    const unsigned short* x2p = x2b + (size_t)bh * S_LEN * D_LEN;
    const unsigned short* x3p = x3s + (size_t)bh * (size_t)D_LEN * S_LEN;
    const int t = threadIdx.x;
    const int w = t >> 6, lane = t & 63, quad = lane >> 4, l16 = lane & 15;
    const int qrow = 16 * w + 4 * quad;       // q row base within tile
    const int cE = qrow >> 3;                 // q chunk idx for sE store
    const int qoff7 = qrow & 7;               // element offset in chunk

#pragma unroll
    for (int i = 0; i < 4; ++i) {  // stage resident sK (64x128), swizzled
        int idx = i * 256 + t;
        int r = idx >> 4, c = idx & 15;
        *(uint4*)&sK[r * 128 + ((c ^ (r & 7)) * 8)] =
            *(const uint4*)&x2p[(size_t)(kb0 + r) * D_LEN + c * 8];
    }

    f32x4 oa[8];  // db(2) x kb(4)
#pragma unroll
    for (int i = 0; i < 8; ++i) oa[i] = (f32x4){0.f, 0.f, 0.f, 0.f};

    __syncthreads();  // sK ready (also gates first sQ/sX stage)

    for (int q0 = 0; q0 < S_LEN; q0 += 64) {
#pragma unroll
        for (int i = 0; i < 4; ++i) {  // stage sQ (64x128), swizzled
            int idx = i * 256 + t;
            int r = idx >> 4, c = idx & 15;
            *(uint4*)&sQ[r * 128 + ((c ^ (r & 7)) * 8)] =
                *(const uint4*)&x1p[(size_t)(q0 + r) * D_LEN + c * 8];
        }
#pragma unroll
        for (int i = 0; i < 4; ++i) {  // stage sX (128d x 64q), swizzled
            int idx = i * 256 + t;
            int r = idx >> 3, c = idx & 7;
            *(uint4*)&sX[r * 64 + ((c ^ (r & 7)) * 8)] =
                *(const uint4*)&x3p[(size_t)r * S_LEN + q0 + c * 8];
        }
        __syncthreads();  // B2: staged

        // QK: 16q x 64k per wave
        f32x4 acc[4];
#pragma unroll
        for (int kb = 0; kb < 4; ++kb) acc[kb] = (f32x4){0.f, 0.f, 0.f, 0.f};
#pragma unroll
        for (int kk = 0; kk < 4; ++kk) {
            const int sc = ((kk * 4 + quad) ^ (l16 & 7)) * 8;
            short8 a = *(const short8*)&sQ[(16 * w + l16) * 128 + sc];
            short8 b[4];
#pragma unroll
            for (int kb = 0; kb < 4; ++kb)
                b[kb] = *(const short8*)&sK[(kb * 16 + l16) * 128 + sc];
#pragma unroll
            for (int kb = 0; kb < 4; ++kb)
                acc[kb] = __builtin_amdgcn_mfma_f32_16x16x32_bf16(a, b[kb], acc[kb], 0, 0, 0);
        }

        // exp to regs; C row = q = qrow+rr, col = k = kb*16+l16
        uint2 pk[4];
#pragma unroll
        for (int kb = 0; kb < 4; ++kb) {
            const int kg = kb0 + kb * 16 + l16;
            float e0 = __expf(acc[kb][0] + bf2f(mbf[(size_t)(q0 + qrow + 0) * S_LEN + kg]));
            float e1 = __expf(acc[kb][1] + bf2f(mbf[(size_t)(q0 + qrow + 1) * S_LEN + kg]));
            float e2 = __expf(acc[kb][2] + bf2f(mbf[(size_t)(q0 + qrow + 2) * S_LEN + kg]));
            float e3 = __expf(acc[kb][3] + bf2f(mbf[(size_t)(q0 + qrow + 3) * S_LEN + kg]));
            pk[kb].x = pack2bf(e0, e1);
            pk[kb].y = pack2bf(e2, e3);
        }

        __syncthreads();  // B3: all QK reads of sQ done (sE aliases sQ)
#pragma unroll
        for (int kb = 0; kb < 4; ++kb) {
            const int krow = kb * 16 + l16;
            *(uint2*)&sE[krow * 64 + ((cE ^ (krow & 7)) * 8) + qoff7] = pk[kb];
        }
        __syncthreads();  // B4: sE ready

        // PV: 32d x 64k per wave (contraction over q)
#pragma unroll
        for (int kk = 0; kk < 2; ++kk) {
            const int sc = ((kk * 4 + quad) ^ (l16 & 7)) * 8;
            short8 a[2];
#pragma unroll
            for (int db = 0; db < 2; ++db)
                a[db] = *(const short8*)&sX[(32 * w + 16 * db + l16) * 64 + sc];
            short8 b[4];
#pragma unroll
            for (int kb = 0; kb < 4; ++kb)
                b[kb] = *(const short8*)&sE[(kb * 16 + l16) * 64 + sc];
#pragma unroll
            for (int db = 0; db < 2; ++db)
#pragma unroll
                for (int kb = 0; kb < 4; ++kb)
                    oa[db * 4 + kb] = __builtin_amdgcn_mfma_f32_16x16x32_bf16(a[db], b[kb], oa[db * 4 + kb], 0, 0, 0);
        }
        __syncthreads();  // B1: PV reads done before next restage of sQ/sX
    }

#pragma unroll
    for (int db = 0; db < 2; ++db)
#pragma unroll
        for (int kb = 0; kb < 4; ++kb)
#pragma unroll
            for (int rr = 0; rr < 4; ++rr) {
                int d = 32 * w + 16 * db + 4 * quad + rr;
                out[((size_t)bh * D_LEN + d) * S_LEN + kb0 + kb * 16 + l16] =
                    oa[db * 4 + kb][rr];
            }
}

// ================= Fallback path (ws too small) =================
__global__ __launch_bounds__(256, 3) void k_rowsum_fb(
    const float* __restrict__ x1, const float* __restrict__ x2,
    const float* __restrict__ mask, float* __restrict__ rl)
{
    __shared__ unsigned short sQ[128 * 136];
    __shared__ unsigned short sK[64 * 136];
    const int q0 = blockIdx.x * 128;
    const int bh = blockIdx.y;
    const float* x1b = x1 + (size_t)bh * S_LEN * D_LEN;
    const float* x2b = x2 + (size_t)bh * S_LEN * D_LEN;
    const int t = threadIdx.x;
    const int w = t >> 6, lane = t & 63, quad = lane >> 4, l16 = lane & 15;
#pragma unroll
    for (int i = 0; i < 16; ++i) {
        int e = (i * 256 + t) * 4;
        int r = e >> 7, c = e & 127;
        float4 v = *(const float4*)&x1b[(size_t)(q0 + r) * D_LEN + c];
        *(uint2*)&sQ[r * 136 + c] = pack4bf(v);
    }
    float rs[8] = {0.f, 0.f, 0.f, 0.f, 0.f, 0.f, 0.f, 0.f};
    for (int k0 = 0; k0 < S_LEN; k0 += 64) {
        __syncthreads();
#pragma unroll
        for (int i = 0; i < 8; ++i) {
            int e = (i * 256 + t) * 4;
            int r = e >> 7, c = e & 127;
            float4 v = *(const float4*)&x2b[(size_t)(k0 + r) * D_LEN + c];
            *(uint2*)&sK[r * 136 + c] = pack4bf(v);
        }
        __syncthreads();
#pragma unroll
        for (int qb = 0; qb < 2; ++qb) {
            const int qrow = 32 * w + 16 * qb;
#pragma unroll
            for (int kb = 0; kb < 4; ++kb) {
                f32x4 acc = {0.f, 0.f, 0.f, 0.f};
#pragma unroll
                for (int kk = 0; kk < 4; ++kk) {
                    short8 a = *(const short8*)&sQ[(qrow + l16) * 136 + kk * 32 + quad * 8];
                    short8 b = *(const short8*)&sK[(kb * 16 + l16) * 136 + kk * 32 + quad * 8];
                    acc = __builtin_amdgcn_mfma_f32_16x16x32_bf16(a, b, acc, 0, 0, 0);
                }
                const int kg = k0 + kb * 16 + l16;
                const int qg = q0 + qrow + 4 * quad;
#pragma unroll
                for (int r = 0; r < 4; ++r) {
                    float m = mask[(size_t)(qg + r) * S_LEN + kg];
                    rs[qb * 4 + r] += __expf(acc[r] * SCALE_QK + m);
                }
            }
        }
    }
#pragma unroll
    for (int i = 0; i < 8; ++i) {
        float v = rs[i];
        v += __shfl_xor(v, 1); v += __shfl_xor(v, 2);
        v += __shfl_xor(v, 4); v += __shfl_xor(v, 8);
        if (l16 == 0) {
            int qg = q0 + 32 * w + 16 * (i >> 2) + 4 * quad + (i & 3);
            rl[(size_t)bh * S_LEN + qg] = 1.0f / v;
        }
    }
}

__global__ __launch_bounds__(256, 2) void k_out_fb(
    const float* __restrict__ x1, const float* __restrict__ x2,
    const float* __restrict__ x3, const float* __restrict__ mask,
    const float* __restrict__ rl, float* __restrict__ out)
{
    __shared__ unsigned short sK[64 * 136];
    __shared__ unsigned short sQ[64 * 136];
    __shared__ unsigned short sX[128 * 72];
    __shared__ unsigned short sE[64 * 72];
    const int kb0 = blockIdx.x * 64;
    const int bh = blockIdx.y;
    const float* x1b = x1 + (size_t)bh * S_LEN * D_LEN;
    const float* x2b = x2 + (size_t)bh * S_LEN * D_LEN;
    const float* x3b = x3 + (size_t)bh * (size_t)D_LEN * S_LEN;
    const float* rlb = rl + (size_t)bh * S_LEN;
    const int t = threadIdx.x;
    const int w = t >> 6, lane = t & 63, quad = lane >> 4, l16 = lane & 15;
#pragma unroll
    for (int i = 0; i < 8; ++i) {
        int e = (i * 256 + t) * 4;
        int r = e >> 7, c = e & 127;
        float4 v = *(const float4*)&x2b[(size_t)(kb0 + r) * D_LEN + c];
        *(uint2*)&sK[r * 136 + c] = pack4bf(v);
    }
    f32x4 oa[8];
#pragma unroll
    for (int i = 0; i < 8; ++i) oa[i] = (f32x4){0.f, 0.f, 0.f, 0.f};
    for (int q0 = 0; q0 < S_LEN; q0 += 64) {
        __syncthreads();
#pragma unroll
        for (int i = 0; i < 8; ++i) {
            int e = (i * 256 + t) * 4;
            int r = e >> 7, c = e & 127;
            float4 v = *(const float4*)&x1b[(size_t)(q0 + r) * D_LEN + c];
            *(uint2*)&sQ[r * 136 + c] = pack4bf(v);
        }
#pragma unroll
        for (int i = 0; i < 8; ++i) {
            int e = (i * 256 + t) * 4;
            int r = e >> 6, c = e & 63;
            float4 v = *(const float4*)&x3b[(size_t)r * S_LEN + q0 + c];
            *(uint2*)&sX[r * 72 + c] = pack4bf(v);
        }
        __syncthreads();
        const int qrow = 16 * w + 4 * quad;
        float rl4[4];
#pragma unroll
        for (int r = 0; r < 4; ++r) rl4[r] = rlb[q0 + qrow + r];
#pragma unroll
        for (int kb = 0; kb < 4; ++kb) {
            f32x4 acc = {0.f, 0.f, 0.f, 0.f};
#pragma unroll
            for (int kk = 0; kk < 4; ++kk) {
                short8 a = *(const short8*)&sQ[(16 * w + l16) * 136 + kk * 32 + quad * 8];
                short8 b = *(const short8*)&sK[(kb * 16 + l16) * 136 + kk * 32 + quad * 8];
                acc = __builtin_amdgcn_mfma_f32_16x16x32_bf16(a, b, acc, 0, 0, 0);
            }
            const int kg = kb0 + kb * 16 + l16;
            unsigned short e4[4];
#pragma unroll
            for (int r = 0; r < 4; ++r) {
                float m = mask[(size_t)(q0 + qrow + r) * S_LEN + kg];
                e4[r] = f2bf(__expf(acc[r] * SCALE_QK + m) * rl4[r]);
            }
            uint2 pk;
            pk.x = (unsigned)e4[0] | ((unsigned)e4[1] << 16);
            pk.y = (unsigned)e4[2] | ((unsigned)e4[3] << 16);
            *(uint2*)&sE[(kb * 16 + l16) * 72 + qrow] = pk;
        }
        __syncthreads();
#pragma unroll
        for (int db = 0; db < 2; ++db)
#pragma unroll
            for (int kb = 0; kb < 4; ++kb) {
                f32x4 a0 = oa[db * 4 + kb];
#pragma unroll
                for (int kk = 0; kk < 2; ++kk) {
                    short8 a = *(const short8*)&sX[(32 * w + 16 * db + l16) * 72 + kk * 32 + quad * 8];
                    short8 b = *(const short8*)&sE[(kb * 16 + l16) * 72 + kk * 32 + quad * 8];
                    a0 = __builtin_amdgcn_mfma_f32_16x16x32_bf16(a, b, a0, 0, 0, 0);
                }
                oa[db * 4 + kb] = a0;
            }
    }
#pragma unroll
    for (int db = 0; db < 2; ++db)
#pragma unroll
        for (int kb = 0; kb < 4; ++kb)
#pragma unroll
            for (int r = 0; r < 4; ++r) {
                int d = 32 * w + 16 * db + 4 * quad + r;
                out[((size_t)bh * D_LEN + d) * S_LEN + kb0 + kb * 16 + l16] =
                    oa[db * 4 + kb][r];
            }
}

extern "C" void kernel_launch(void* const* d_in, const int* in_sizes, int n_in,
                              void* d_out, int out_size, void* d_ws, size_t ws_size,
                              hipStream_t stream) {
    const float* x1 = (const float*)d_in[0];
    const float* x2 = (const float*)d_in[1];
    const float* x3 = (const float*)d_in[2];
    const float* mask = (const float*)d_in[3];
    float* out = (float*)d_out;

    const size_t N1 = (size_t)BH_N * S_LEN * D_LEN;
    const size_t NM = (size_t)S_LEN * S_LEN;
    const size_t need = (3 * N1 + NM) * sizeof(unsigned short);  // 58.7 MB

    if (ws_size >= need) {
        unsigned short* x1s = (unsigned short*)d_ws;
        unsigned short* x2b = x1s + N1;
        unsigned short* x3s = x2b + N1;
        unsigned short* mbf = x3s + N1;
        const size_t tot4 = (2 * N1 + NM) / 4;
        k_cvt<<<dim3((unsigned)(tot4 / 256)), dim3(256), 0, stream>>>(x1, x2, mask, x1s, x2b, mbf);
        k_qk<<<dim3(S_LEN / 64, BH_N), dim3(256), 0, stream>>>(x1s, x2b, mbf, x3, x3s);
        k_out<<<dim3(S_LEN / 64, BH_N), dim3(256), 0, stream>>>(x1s, x2b, x3s, mbf, out);
    } else {
        float* rl = (float*)d_ws;
        k_rowsum_fb<<<dim3(S_LEN / 128, BH_N), dim3(256), 0, stream>>>(x1, x2, mask, rl);
        k_out_fb<<<dim3(S_LEN / 64, BH_N), dim3(256), 0, stream>>>(x1, x2, x3, mask, rl, out);
    }
}

// Round 8
// 310.433 us; speedup vs baseline: 1.2478x; 1.2478x over previous
//
#include <hip/hip_runtime.h>

// B=2,H=16,S=2048,D=128 (f32 I/O; internal bf16 MFMA)
//   qk = x1·x2^T*scale + mask;  P = softmax_k(qk);  out = x3 @ P
// ws (58.7 MB): x1s=bf16(x1*scale), x2b=bf16(x2), x3s=bf16(x3*rl), mbf=bf16(mask)
//   k_qk : q-stripe 64, 4 blocks/CU (R7 win, 139us). R8: wave decomposition
//          2q x 2k — wave w owns (qh=w&1: 32 q rows, kh=w>>1: 64 k cols),
//          acc[2][4], aq[2][4] in regs. Each sK fragment feeds 2 MFMAs ->
//          0.5 ds_read/MFMA (was 1.0; k_qk is LDS-read-throughput bound:
//          16 waves x 32 reads x 12cyc >> MFMA cycles). Rowsum: l16-shfl ->
//          sRSp[4][32] -> cross-kh combine.
//   k_out: R4's 115.1us version BYTE-IDENTICAL (128-k block, 2 barriers/iter).
//          R7's 64-k + sE-alias 4-barrier variant cost ~2x (228us) — small
//          work quanta between barriers; structure is load-bearing.
//   exp via __expf; bf16 pack via pack2bf (v_perm) in k_cvt/k_qk epilogue;
//   k_out keeps R4's manual f2bf path (measured).
// LDS swizzle: 16B chunk c of row r stored at (c ^ (r&7)) -> bank-uniform.

typedef __attribute__((ext_vector_type(8))) short short8;
typedef __attribute__((ext_vector_type(4))) float f32x4;

#define S_LEN 2048
#define D_LEN 128
#define BH_N 32
#define SCALE_QK 0.08838834764831845f

__device__ __forceinline__ unsigned short f2bf(float f) {
    union { float f; unsigned int i; } v; v.f = f;
    unsigned int r = v.i + 0x7FFFu + ((v.i >> 16) & 1u);  // RNE
    return (unsigned short)(r >> 16);
}
__device__ __forceinline__ float bf2f(unsigned short u) {
    union { unsigned int i; float f; } v; v.i = ((unsigned int)u) << 16; return v.f;
}
// pack two f32 -> two bf16 (round-half-up): 2 adds + 1 v_perm
__device__ __forceinline__ unsigned pack2bf(float a, float b) {
    unsigned ua = __float_as_uint(a) + 0x8000u;
    unsigned ub = __float_as_uint(b) + 0x8000u;
    return __builtin_amdgcn_perm(ub, ua, 0x07060302);  // [ua.b2,ua.b3,ub.b2,ub.b3]
}
__device__ __forceinline__ uint2 pack4bf(float4 v) {
    uint2 p;
    p.x = pack2bf(v.x, v.y);
    p.y = pack2bf(v.z, v.w);
    return p;
}

// ---------- Kernel 0: one-time f32 -> bf16 conversions ----------
__global__ void k_cvt(const float* __restrict__ x1,
                      const float* __restrict__ x2,
                      const float* __restrict__ mask,
                      unsigned short* __restrict__ x1s,
                      unsigned short* __restrict__ x2b,
                      unsigned short* __restrict__ mbf) {
    const size_t N1 = (size_t)BH_N * S_LEN * D_LEN;
    const size_t NM = (size_t)S_LEN * S_LEN;
    size_t i = ((size_t)blockIdx.x * 256 + threadIdx.x) * 4;
    if (i < N1) {
        float4 v = *(const float4*)&x1[i];
        v.x *= SCALE_QK; v.y *= SCALE_QK; v.z *= SCALE_QK; v.w *= SCALE_QK;
        *(uint2*)&x1s[i] = pack4bf(v);
    } else if (i < 2 * N1) {
        size_t j = i - N1;
        float4 v = *(const float4*)&x2[j];
        *(uint2*)&x2b[j] = pack4bf(v);
    } else if (i < 2 * N1 + NM) {
        size_t j = i - 2 * N1;
        float4 v = *(const float4*)&mask[j];
        *(uint2*)&mbf[j] = pack4bf(v);
    }
}

// ---------- Kernel 1: rowsums (C[q][k], 2q x 2k waves) + x3s stripe ----------
// grid(32, 32): x = 64-row q stripe, y = bh. 4 waves, 4 blocks/CU.
// Wave w: qh=w&1 -> q rows [32qh,32qh+32); kh=w>>1 -> k cols [64kh,64kh+64).
__global__ __launch_bounds__(256, 4) void k_qk(
    const unsigned short* __restrict__ x1s,
    const unsigned short* __restrict__ x2b,
    const unsigned short* __restrict__ mbf,
    const float* __restrict__ x3,
    unsigned short* __restrict__ x3s)
{
    __shared__ unsigned short sK[128 * 128];  // k x d bf16 (per-iter, swizzled)
    __shared__ float sRSp[4][32];             // per-wave row partials
    __shared__ float sRL[64];
    const int q0 = blockIdx.x * 64;
    const int bh = blockIdx.y;
    const unsigned short* x1p = x1s + (size_t)bh * S_LEN * D_LEN;
    const unsigned short* x2p = x2b + (size_t)bh * S_LEN * D_LEN;
    const int t = threadIdx.x;
    const int w = t >> 6, lane = t & 63, quad = lane >> 4, l16 = lane & 15;
    const int qh = w & 1, kh = w >> 1;

    // Q fragments in registers: wave-private, iteration-invariant. 32 VGPRs.
    short8 aq[2][4];
#pragma unroll
    for (int qb = 0; qb < 2; ++qb)
#pragma unroll
        for (int kk = 0; kk < 4; ++kk)
            aq[qb][kk] = *(const short8*)&x1p[(size_t)(q0 + 32 * qh + 16 * qb + l16) * D_LEN
                                              + (kk * 4 + quad) * 8];

    float rs[8] = {0.f, 0.f, 0.f, 0.f, 0.f, 0.f, 0.f, 0.f};

    for (int k0 = 0; k0 < S_LEN; k0 += 128) {
        __syncthreads();
#pragma unroll
        for (int i = 0; i < 8; ++i) {  // stage sK (128x128), swizzled
            int idx = i * 256 + t;
            int r = idx >> 4, c = idx & 15;
            *(uint4*)&sK[r * 128 + ((c ^ (r & 7)) * 8)] =
                *(const uint4*)&x2p[(size_t)(k0 + r) * D_LEN + c * 8];
        }
        __syncthreads();

        f32x4 acc[2][4];
#pragma unroll
        for (int qb = 0; qb < 2; ++qb)
#pragma unroll
            for (int kb = 0; kb < 4; ++kb) acc[qb][kb] = (f32x4){0.f, 0.f, 0.f, 0.f};

#pragma unroll
        for (int kk = 0; kk < 4; ++kk) {
            const int sc = ((kk * 4 + quad) ^ (l16 & 7)) * 8;
            short8 b[4];
#pragma unroll
            for (int kb = 0; kb < 4; ++kb)
                b[kb] = *(const short8*)&sK[(64 * kh + kb * 16 + l16) * 128 + sc];
#pragma unroll
            for (int qb = 0; qb < 2; ++qb)
#pragma unroll
                for (int kb = 0; kb < 4; ++kb)
                    acc[qb][kb] = __builtin_amdgcn_mfma_f32_16x16x32_bf16(aq[qb][kk], b[kb], acc[qb][kb], 0, 0, 0);
        }

        // exp + rowsum; C row = q = 32qh+16qb+4quad+rr, col = k0+64kh+kb*16+l16
#pragma unroll
        for (int qb = 0; qb < 2; ++qb)
#pragma unroll
            for (int kb = 0; kb < 4; ++kb) {
                const size_t mrow = (size_t)(q0 + 32 * qh + 16 * qb + 4 * quad) * S_LEN
                                    + k0 + 64 * kh + kb * 16 + l16;
#pragma unroll
                for (int rr = 0; rr < 4; ++rr)
                    rs[qb * 4 + rr] += __expf(acc[qb][kb][rr] + bf2f(mbf[mrow + (size_t)rr * S_LEN]));
            }
    }

    // reduce over l16, then combine the two k-half waves per q row
#pragma unroll
    for (int i = 0; i < 8; ++i) {
        float v = rs[i];
        v += __shfl_xor(v, 1); v += __shfl_xor(v, 2);
        v += __shfl_xor(v, 4); v += __shfl_xor(v, 8);
        if (l16 == 0) sRSp[w][16 * (i >> 2) + 4 * quad + (i & 3)] = v;
    }
    __syncthreads();
    if (t < 64) {
        int qh_ = t >> 5, rl_ = t & 31;
        sRL[t] = 1.0f / (sRSp[qh_][rl_] + sRSp[qh_ + 2][rl_]);
    }
    __syncthreads();

    // x3s[:, q0:q0+64] = bf16(x3 * rl)
    const float* x3b = x3 + (size_t)bh * (size_t)D_LEN * S_LEN;
    unsigned short* x3sp = x3s + (size_t)bh * (size_t)D_LEN * S_LEN;
#pragma unroll
    for (int i = 0; i < 8; ++i) {
        int e = (i * 256 + t) * 4;
        int r = e >> 6, c = e & 63;
        float4 v = *(const float4*)&x3b[(size_t)r * S_LEN + q0 + c];
        v.x *= sRL[c]; v.y *= sRL[c + 1]; v.z *= sRL[c + 2]; v.w *= sRL[c + 3];
        *(uint2*)&x3sp[(size_t)r * S_LEN + q0 + c] = pack4bf(v);
    }
}

// ---------- Kernel 2: out = x3s @ exp(QK + mask), 128-k blocks ----------
// R4's 115us version, byte-identical.
// grid(16, 32): x = 128-col k block, y = bh. 4 waves.
// QK: wave w owns q rows [16w,16w+16) x 128k. PV: wave w owns d [32w,32w+32).
__global__ __launch_bounds__(256, 2) void k_out(
    const unsigned short* __restrict__ x1s,
    const unsigned short* __restrict__ x2b,
    const unsigned short* __restrict__ x3s,
    const unsigned short* __restrict__ mbf,
    float* __restrict__ out)
{
    __shared__ unsigned short sK[128 * 128];  // x2 k-block (resident, swizzled)
    __shared__ unsigned short sQ[64 * 128];   // x1 q-tile (swizzled)
    __shared__ unsigned short sX[128 * 64];   // x3s tile d x q (swizzled)
    __shared__ unsigned short sE[128 * 64];   // E^T k x q (swizzled)
    const int kb0 = blockIdx.x * 128;
    const int bh = blockIdx.y;
    const unsigned short* x1p = x1s + (size_t)bh * S_LEN * D_LEN;
    const unsigned short* x2p = x2b + (size_t)bh * S_LEN * D_LEN;
    const unsigned short* x3p = x3s + (size_t)bh * (size_t)D_LEN * S_LEN;
    const int t = threadIdx.x;
    const int w = t >> 6, lane = t & 63, quad = lane >> 4, l16 = lane & 15;

#pragma unroll
    for (int i = 0; i < 8; ++i) {  // stage resident sK (128x128), swizzled
        int idx = i * 256 + t;
        int r = idx >> 4, c = idx & 15;
        *(uint4*)&sK[r * 128 + ((c ^ (r & 7)) * 8)] =
            *(const uint4*)&x2p[(size_t)(kb0 + r) * D_LEN + c * 8];
    }

    f32x4 oa[16];  // db(2) x kb(8)
#pragma unroll
    for (int i = 0; i < 16; ++i) oa[i] = (f32x4){0.f, 0.f, 0.f, 0.f};

    for (int q0 = 0; q0 < S_LEN; q0 += 64) {
        __syncthreads();
#pragma unroll
        for (int i = 0; i < 4; ++i) {  // stage sQ (64x128), swizzled
            int idx = i * 256 + t;
            int r = idx >> 4, c = idx & 15;
            *(uint4*)&sQ[r * 128 + ((c ^ (r & 7)) * 8)] =
                *(const uint4*)&x1p[(size_t)(q0 + r) * D_LEN + c * 8];
        }
#pragma unroll
        for (int i = 0; i < 4; ++i) {  // stage sX (128d x 64q), swizzled
            int idx = i * 256 + t;
            int r = idx >> 3, c = idx & 7;
            *(uint4*)&sX[r * 64 + ((c ^ (r & 7)) * 8)] =
                *(const uint4*)&x3p[(size_t)r * S_LEN + q0 + c * 8];
        }
        __syncthreads();

        // QK: 16q x 128k per wave
        f32x4 acc[8];
#pragma unroll
        for (int kb = 0; kb < 8; ++kb) acc[kb] = (f32x4){0.f, 0.f, 0.f, 0.f};
#pragma unroll
        for (int kk = 0; kk < 4; ++kk) {
            const int sc = ((kk * 4 + quad) ^ (l16 & 7)) * 8;
            short8 a = *(const short8*)&sQ[(16 * w + l16) * 128 + sc];
            short8 b[8];
#pragma unroll
            for (int kb = 0; kb < 8; ++kb)
                b[kb] = *(const short8*)&sK[(kb * 16 + l16) * 128 + sc];
#pragma unroll
            for (int kb = 0; kb < 8; ++kb)
                acc[kb] = __builtin_amdgcn_mfma_f32_16x16x32_bf16(a, b[kb], acc[kb], 0, 0, 0);
        }
        // exp + sE^T store; C row = q = 16w+4quad+r, col = k = kb*16+l16
        const int qrow = 16 * w + 4 * quad;
        const int qoff7 = (16 * w + 4 * quad) & 7;          // 8B offset in chunk
        const int cE = (16 * w + 4 * quad) >> 3;            // q chunk idx
#pragma unroll
        for (int kb = 0; kb < 8; ++kb) {
            const int kg = kb0 + kb * 16 + l16;
            unsigned short e4[4];
#pragma unroll
            for (int r = 0; r < 4; ++r) {
                float m = bf2f(mbf[(size_t)(q0 + qrow + r) * S_LEN + kg]);
                e4[r] = f2bf(__expf(acc[kb][r] + m));
            }
            uint2 pk;
            pk.x = (unsigned)e4[0] | ((unsigned)e4[1] << 16);
            pk.y = (unsigned)e4[2] | ((unsigned)e4[3] << 16);
            const int krow = kb * 16 + l16;
            *(uint2*)&sE[krow * 64 + ((cE ^ (krow & 7)) * 8) + qoff7] = pk;
        }
        __syncthreads();

        // PV: 32d x 128k per wave
#pragma unroll
        for (int kk = 0; kk < 2; ++kk) {
            const int sc = ((kk * 4 + quad) ^ (l16 & 7)) * 8;
            short8 a[2];
#pragma unroll
            for (int db = 0; db < 2; ++db)
                a[db] = *(const short8*)&sX[(32 * w + 16 * db + l16) * 64 + sc];
            short8 b[8];
#pragma unroll
            for (int kb = 0; kb < 8; ++kb)
                b[kb] = *(const short8*)&sE[(kb * 16 + l16) * 64 + sc];
#pragma unroll
            for (int db = 0; db < 2; ++db)
#pragma unroll
                for (int kb = 0; kb < 8; ++kb)
                    oa[db * 8 + kb] = __builtin_amdgcn_mfma_f32_16x16x32_bf16(a[db], b[kb], oa[db * 8 + kb], 0, 0, 0);
        }
    }

#pragma unroll
    for (int db = 0; db < 2; ++db)
#pragma unroll
        for (int kb = 0; kb < 8; ++kb)
#pragma unroll
            for (int r = 0; r < 4; ++r) {
                int d = 32 * w + 16 * db + 4 * quad + r;
                out[((size_t)bh * D_LEN + d) * S_LEN + kb0 + kb * 16 + l16] =
                    oa[db * 8 + kb][r];
            }
}

// ================= Fallback path (ws too small) =================
__global__ __launch_bounds__(256, 3) void k_rowsum_fb(
    const float* __restrict__ x1, const float* __restrict__ x2,
    const float* __restrict__ mask, float* __restrict__ rl)
{
    __shared__ unsigned short sQ[128 * 136];
    __shared__ unsigned short sK[64 * 136];
    const int q0 = blockIdx.x * 128;
    const int bh = blockIdx.y;
    const float* x1b = x1 + (size_t)bh * S_LEN * D_LEN;
    const float* x2b = x2 + (size_t)bh * S_LEN * D_LEN;
    const int t = threadIdx.x;
    const int w = t >> 6, lane = t & 63, quad = lane >> 4, l16 = lane & 15;
#pragma unroll
    for (int i = 0; i < 16; ++i) {
        int e = (i * 256 + t) * 4;
        int r = e >> 7, c = e & 127;
        float4 v = *(const float4*)&x1b[(size_t)(q0 + r) * D_LEN + c];
        *(uint2*)&sQ[r * 136 + c] = pack4bf(v);
    }
    float rs[8] = {0.f, 0.f, 0.f, 0.f, 0.f, 0.f, 0.f, 0.f};
    for (int k0 = 0; k0 < S_LEN; k0 += 64) {
        __syncthreads();
#pragma unroll
        for (int i = 0; i < 8; ++i) {
            int e = (i * 256 + t) * 4;
            int r = e >> 7, c = e & 127;
            float4 v = *(const float4*)&x2b[(size_t)(k0 + r) * D_LEN + c];
            *(uint2*)&sK[r * 136 + c] = pack4bf(v);
        }
        __syncthreads();
#pragma unroll
        for (int qb = 0; qb < 2; ++qb) {
            const int qrow = 32 * w + 16 * qb;
#pragma unroll
            for (int kb = 0; kb < 4; ++kb) {
                f32x4 acc = {0.f, 0.f, 0.f, 0.f};
#pragma unroll
                for (int kk = 0; kk < 4; ++kk) {
                    short8 a = *(const short8*)&sQ[(qrow + l16) * 136 + kk * 32 + quad * 8];
                    short8 b = *(const short8*)&sK[(kb * 16 + l16) * 136 + kk * 32 + quad * 8];
                    acc = __builtin_amdgcn_mfma_f32_16x16x32_bf16(a, b, acc, 0, 0, 0);
                }
                const int kg = k0 + kb * 16 + l16;
                const int qg = q0 + qrow + 4 * quad;
#pragma unroll
                for (int r = 0; r < 4; ++r) {
                    float m = mask[(size_t)(qg + r) * S_LEN + kg];
                    rs[qb * 4 + r] += __expf(acc[r] * SCALE_QK + m);
                }
            }
        }
    }
#pragma unroll
    for (int i = 0; i < 8; ++i) {
        float v = rs[i];
        v += __shfl_xor(v, 1); v += __shfl_xor(v, 2);
        v += __shfl_xor(v, 4); v += __shfl_xor(v, 8);
        if (l16 == 0) {
            int qg = q0 + 32 * w + 16 * (i >> 2) + 4 * quad + (i & 3);
            rl[(size_t)bh * S_LEN + qg] = 1.0f / v;
        }
    }
}

__global__ __launch_bounds__(256, 2) void k_out_fb(
    const float* __restrict__ x1, const float* __restrict__ x2,
    const float* __restrict__ x3, const float* __restrict__ mask,
    const float* __restrict__ rl, float* __restrict__ out)
{
    __shared__ unsigned short sK[64 * 136];
    __shared__ unsigned short sQ[64 * 136];
    __shared__ unsigned short sX[128 * 72];
    __shared__ unsigned short sE[64 * 72];
    const int kb0 = blockIdx.x * 64;
    const int bh = blockIdx.y;
    const float* x1b = x1 + (size_t)bh * S_LEN * D_LEN;
    const float* x2b = x2 + (size_t)bh * S_LEN * D_LEN;
    const float* x3b = x3 + (size_t)bh * (size_t)D_LEN * S_LEN;
    const float* rlb = rl + (size_t)bh * S_LEN;
    const int t = threadIdx.x;
    const int w = t >> 6, lane = t & 63, quad = lane >> 4, l16 = lane & 15;
#pragma unroll
    for (int i = 0; i < 8; ++i) {
        int e = (i * 256 + t) * 4;
        int r = e >> 7, c = e & 127;
        float4 v = *(const float4*)&x2b[(size_t)(kb0 + r) * D_LEN + c];
        *(uint2*)&sK[r * 136 + c] = pack4bf(v);
    }
    f32x4 oa[8];
#pragma unroll
    for (int i = 0; i < 8; ++i) oa[i] = (f32x4){0.f, 0.f, 0.f, 0.f};
    for (int q0 = 0; q0 < S_LEN; q0 += 64) {
        __syncthreads();
#pragma unroll
        for (int i = 0; i < 8; ++i) {
            int e = (i * 256 + t) * 4;
            int r = e >> 7, c = e & 127;
            float4 v = *(const float4*)&x1b[(size_t)(q0 + r) * D_LEN + c];
            *(uint2*)&sQ[r * 136 + c] = pack4bf(v);
        }
#pragma unroll
        for (int i = 0; i < 8; ++i) {
            int e = (i * 256 + t) * 4;
            int r = e >> 6, c = e & 63;
            float4 v = *(const float4*)&x3b[(size_t)r * S_LEN + q0 + c];
            *(uint2*)&sX[r * 72 + c] = pack4bf(v);
        }
        __syncthreads();
        const int qrow = 16 * w + 4 * quad;
        float rl4[4];
#pragma unroll
        for (int r = 0; r < 4; ++r) rl4[r] = rlb[q0 + qrow + r];
#pragma unroll
        for (int kb = 0; kb < 4; ++kb) {
            f32x4 acc = {0.f, 0.f, 0.f, 0.f};
#pragma unroll
            for (int kk = 0; kk < 4; ++kk) {
                short8 a = *(const short8*)&sQ[(16 * w + l16) * 136 + kk * 32 + quad * 8];
                short8 b = *(const short8*)&sK[(kb * 16 + l16) * 136 + kk * 32 + quad * 8];
                acc = __builtin_amdgcn_mfma_f32_16x16x32_bf16(a, b, acc, 0, 0, 0);
            }
            const int kg = kb0 + kb * 16 + l16;
            unsigned short e4[4];
#pragma unroll
            for (int r = 0; r < 4; ++r) {
                float m = mask[(size_t)(q0 + qrow + r) * S_LEN + kg];
                e4[r] = f2bf(__expf(acc[r] * SCALE_QK + m) * rl4[r]);
            }
            uint2 pk;
            pk.x = (unsigned)e4[0] | ((unsigned)e4[1] << 16);
            pk.y = (unsigned)e4[2] | ((unsigned)e4[3] << 16);
            *(uint2*)&sE[(kb * 16 + l16) * 72 + qrow] = pk;
        }
        __syncthreads();
#pragma unroll
        for (int db = 0; db < 2; ++db)
#pragma unroll
            for (int kb = 0; kb < 4; ++kb) {
                f32x4 a0 = oa[db * 4 + kb];
#pragma unroll
                for (int kk = 0; kk < 2; ++kk) {
                    short8 a = *(const short8*)&sX[(32 * w + 16 * db + l16) * 72 + kk * 32 + quad * 8];
                    short8 b = *(const short8*)&sE[(kb * 16 + l16) * 72 + kk * 32 + quad * 8];
                    a0 = __builtin_amdgcn_mfma_f32_16x16x32_bf16(a, b, a0, 0, 0, 0);
                }
                oa[db * 4 + kb] = a0;
            }
    }
#pragma unroll
    for (int db = 0; db < 2; ++db)
#pragma unroll
        for (int kb = 0; kb < 4; ++kb)
#pragma unroll
            for (int r = 0; r < 4; ++r) {
                int d = 32 * w + 16 * db + 4 * quad + r;
                out[((size_t)bh * D_LEN + d) * S_LEN + kb0 + kb * 16 + l16] =
                    oa[db * 4 + kb][r];
            }
}

extern "C" void kernel_launch(void* const* d_in, const int* in_sizes, int n_in,
                              void* d_out, int out_size, void* d_ws, size_t ws_size,
                              hipStream_t stream) {
    const float* x1 = (const float*)d_in[0];
    const float* x2 = (const float*)d_in[1];
    const float* x3 = (const float*)d_in[2];
    const float* mask = (const float*)d_in[3];
    float* out = (float*)d_out;

    const size_t N1 = (size_t)BH_N * S_LEN * D_LEN;
    const size_t NM = (size_t)S_LEN * S_LEN;
    const size_t need = (3 * N1 + NM) * sizeof(unsigned short);  // 58.7 MB

    if (ws_size >= need) {
        unsigned short* x1s = (unsigned short*)d_ws;
        unsigned short* x2b = x1s + N1;
        unsigned short* x3s = x2b + N1;
        unsigned short* mbf = x3s + N1;
        const size_t tot4 = (2 * N1 + NM) / 4;
        k_cvt<<<dim3((unsigned)(tot4 / 256)), dim3(256), 0, stream>>>(x1, x2, mask, x1s, x2b, mbf);
        k_qk<<<dim3(S_LEN / 64, BH_N), dim3(256), 0, stream>>>(x1s, x2b, mbf, x3, x3s);
        k_out<<<dim3(S_LEN / 128, BH_N), dim3(256), 0, stream>>>(x1s, x2b, x3s, mbf, out);
    } else {
        float* rl = (float*)d_ws;
        k_rowsum_fb<<<dim3(S_LEN / 128, BH_N), dim3(256), 0, stream>>>(x1, x2, mask, rl);
        k_out_fb<<<dim3(S_LEN / 64, BH_N), dim3(256), 0, stream>>>(x1, x2, x3, mask, rl, out);
    }
}